// Round 1
// baseline (7752.834 us; speedup 1.0000x reference)
//
#include <hip/hip_runtime.h>
#include <math.h>

#define F_IN 32
#define NH 8
#define C1 8
#define D1 64
#define NEG 0.2f

__device__ __forceinline__ void atomicMaxFloat(float* addr, float val) {
    // works for any sign mix when initialized to -inf:
    // positive floats compare correctly as int; negative floats reverse-order as uint
    if (val >= 0.0f) atomicMax((int*)addr, __float_as_int(val));
    else             atomicMin((unsigned int*)addr, __float_as_uint(val));
}

__global__ void k_init(float* __restrict__ ws, int ninf, int total) {
    int i = blockIdx.x * blockDim.x + threadIdx.x;
    int stride = gridDim.x * blockDim.x;
    for (; i < total; i += stride) ws[i] = (i < ninf) ? -INFINITY : 0.0f;
}

// thread per (node, head): h1 row block, attention logits
__global__ void k_node1(const float* __restrict__ x, const float* __restrict__ W1,
                        const float* __restrict__ as1, const float* __restrict__ ad1,
                        float* __restrict__ h1, float* __restrict__ a_s, float* __restrict__ a_d,
                        int N) {
    __shared__ float sW[F_IN * D1];
    __shared__ float sA[2 * D1];
    for (int i = threadIdx.x; i < F_IN * D1; i += blockDim.x) sW[i] = W1[i];
    if (threadIdx.x < 2 * D1)
        sA[threadIdx.x] = (threadIdx.x < D1) ? as1[threadIdx.x] : ad1[threadIdx.x - D1];
    __syncthreads();
    int t = blockIdx.x * blockDim.x + threadIdx.x;
    int n = t >> 3, h = t & 7;
    if (n >= N) return;
    float xr[F_IN];
    const float4* xv = (const float4*)(x + n * F_IN);
#pragma unroll
    for (int k = 0; k < F_IN / 4; ++k) {
        float4 v = xv[k];
        xr[4 * k] = v.x; xr[4 * k + 1] = v.y; xr[4 * k + 2] = v.z; xr[4 * k + 3] = v.w;
    }
    float acc[C1];
#pragma unroll
    for (int c = 0; c < C1; ++c) acc[c] = 0.0f;
#pragma unroll
    for (int k = 0; k < F_IN; ++k) {
        float xk = xr[k];
#pragma unroll
        for (int c = 0; c < C1; ++c) acc[c] = fmaf(xk, sW[k * D1 + h * C1 + c], acc[c]);
    }
    float s_ = 0.0f, d_ = 0.0f;
#pragma unroll
    for (int c = 0; c < C1; ++c) {
        h1[n * D1 + h * C1 + c] = acc[c];
        s_ = fmaf(acc[c], sA[h * C1 + c], s_);
        d_ = fmaf(acc[c], sA[D1 + h * C1 + c], d_);
    }
    a_s[n * NH + h] = s_;
    a_d[n * NH + h] = d_;
}

// thread per edge: segment max of leaky_relu logits, 8 heads
__global__ void k_edge1_max(const int* __restrict__ ei, int E, int Et,
                            const float* __restrict__ a_s, const float* __restrict__ a_d,
                            float* __restrict__ m1) {
    int i = blockIdx.x * blockDim.x + threadIdx.x;
    if (i >= Et) return;
    int s, d;
    if (i < E) { s = ei[i]; d = ei[E + i]; } else { s = i - E; d = s; }
#pragma unroll
    for (int h = 0; h < NH; ++h) {
        float e = a_s[s * NH + h] + a_d[d * NH + h];
        e = e > 0.0f ? e : NEG * e;
        atomicMaxFloat(&m1[d * NH + h], e);
    }
}

// thread per (edge, head): ex = exp(e - m), accumulate denom and unnormalized messages
__global__ void k_edge1_acc(const int* __restrict__ ei, int E, int Et,
                            const float* __restrict__ a_s, const float* __restrict__ a_d,
                            const float* __restrict__ m1, const float* __restrict__ h1,
                            float* __restrict__ denom, float* __restrict__ acc) {
    int t = blockIdx.x * blockDim.x + threadIdx.x;
    if (t >= Et * NH) return;
    int i = t >> 3, h = t & 7;
    int s, d;
    if (i < E) { s = ei[i]; d = ei[E + i]; } else { s = i - E; d = s; }
    float e = a_s[s * NH + h] + a_d[d * NH + h];
    e = e > 0.0f ? e : NEG * e;
    float ex = expf(e - m1[d * NH + h]);
    atomicAdd(&denom[d * NH + h], ex);
    const float* hs = h1 + s * D1 + h * C1;
    float* ap = acc + d * D1 + h * C1;
#pragma unroll
    for (int c = 0; c < C1; ++c) atomicAdd(&ap[c], ex * hs[c]);
}

// thread per node: normalize, +b1, ELU, h2 = helu @ W2, layer-2 logits (all fused)
__global__ void k_node2(const float* __restrict__ acc, const float* __restrict__ denom,
                        const float* __restrict__ b1, const float* __restrict__ W2,
                        const float* __restrict__ as2, const float* __restrict__ ad2,
                        float* __restrict__ h2, float* __restrict__ a_s2, float* __restrict__ a_d2,
                        int N) {
    __shared__ float sW2[D1 * 2];
    __shared__ float sb1[D1];
    __shared__ float sa[4];
    for (int i = threadIdx.x; i < D1 * 2; i += blockDim.x) sW2[i] = W2[i];
    if (threadIdx.x < D1) sb1[threadIdx.x] = b1[threadIdx.x];
    if (threadIdx.x < 2) { sa[threadIdx.x] = as2[threadIdx.x]; sa[2 + threadIdx.x] = ad2[threadIdx.x]; }
    __syncthreads();
    int n = blockIdx.x * blockDim.x + threadIdx.x;
    if (n >= N) return;
    float o0 = 0.0f, o1 = 0.0f;
#pragma unroll
    for (int h = 0; h < NH; ++h) {
        float inv = 1.0f / denom[n * NH + h];
#pragma unroll
        for (int c = 0; c < C1; ++c) {
            int j = h * C1 + c;
            float v = acc[n * D1 + j] * inv + sb1[j];
            v = v > 0.0f ? v : expm1f(v);  // ELU(alpha=1)
            o0 = fmaf(v, sW2[j * 2 + 0], o0);
            o1 = fmaf(v, sW2[j * 2 + 1], o1);
        }
    }
    h2[n * 2 + 0] = o0;
    h2[n * 2 + 1] = o1;
    a_s2[n] = o0 * sa[0] + o1 * sa[1];
    a_d2[n] = o0 * sa[2] + o1 * sa[3];
}

__global__ void k_edge2_max(const int* __restrict__ ei, int E, int Et,
                            const float* __restrict__ a_s2, const float* __restrict__ a_d2,
                            float* __restrict__ m2) {
    int i = blockIdx.x * blockDim.x + threadIdx.x;
    if (i >= Et) return;
    int s, d;
    if (i < E) { s = ei[i]; d = ei[E + i]; } else { s = i - E; d = s; }
    float e = a_s2[s] + a_d2[d];
    e = e > 0.0f ? e : NEG * e;
    atomicMaxFloat(&m2[d], e);
}

__global__ void k_edge2_acc(const int* __restrict__ ei, int E, int Et,
                            const float* __restrict__ a_s2, const float* __restrict__ a_d2,
                            const float* __restrict__ m2, const float* __restrict__ h2,
                            float* __restrict__ denom2, float* __restrict__ acc2) {
    int i = blockIdx.x * blockDim.x + threadIdx.x;
    if (i >= Et) return;
    int s, d;
    if (i < E) { s = ei[i]; d = ei[E + i]; } else { s = i - E; d = s; }
    float e = a_s2[s] + a_d2[d];
    e = e > 0.0f ? e : NEG * e;
    float ex = expf(e - m2[d]);
    atomicAdd(&denom2[d], ex);
    atomicAdd(&acc2[d * 2 + 0], ex * h2[s * 2 + 0]);
    atomicAdd(&acc2[d * 2 + 1], ex * h2[s * 2 + 1]);
}

__global__ void k_final(const float* __restrict__ acc2, const float* __restrict__ denom2,
                        const float* __restrict__ b2, float* __restrict__ out, int N) {
    int n = blockIdx.x * blockDim.x + threadIdx.x;
    if (n >= N) return;
    float inv = 1.0f / denom2[n];
    float o0 = acc2[n * 2 + 0] * inv + b2[0];
    float o1 = acc2[n * 2 + 1] * inv + b2[1];
    float mx = fmaxf(o0, o1);
    float lse = mx + logf(expf(o0 - mx) + expf(o1 - mx));
    out[n * 2 + 0] = o0 - lse;
    out[n * 2 + 1] = o1 - lse;
}

extern "C" void kernel_launch(void* const* d_in, const int* in_sizes, int n_in,
                              void* d_out, int out_size, void* d_ws, size_t ws_size,
                              hipStream_t stream) {
    const float* x   = (const float*)d_in[0];
    const int*   ei  = (const int*)d_in[1];
    const float* W1  = (const float*)d_in[2];
    const float* as1 = (const float*)d_in[3];
    const float* ad1 = (const float*)d_in[4];
    const float* b1  = (const float*)d_in[5];
    const float* W2  = (const float*)d_in[6];
    const float* as2 = (const float*)d_in[7];
    const float* ad2 = (const float*)d_in[8];
    const float* b2  = (const float*)d_in[9];
    float* out = (float*)d_out;

    const int N  = in_sizes[0] / F_IN;   // 100000
    const int E  = in_sizes[1] / 2;      // 3200000
    const int Et = E + N;                // + self-loops

    float* ws     = (float*)d_ws;
    float* m1     = ws;                  // N*8
    float* m2     = m1 + N * NH;         // N
    float* denom1 = m2 + N;              // N*8
    float* denom2 = denom1 + N * NH;     // N
    float* acc1   = denom2 + N;          // N*64
    float* acc2   = acc1 + N * D1;       // N*2
    float* h1     = acc2 + N * 2;        // N*64
    float* a_s1   = h1 + N * D1;         // N*8
    float* a_d1   = a_s1 + N * NH;       // N*8
    float* h2     = a_d1 + N * NH;       // N*2
    float* a_s2   = h2 + N * 2;          // N
    float* a_d2   = a_s2 + N;            // N

    const int ninf   = N * NH + N;                                // m1 + m2
    const int ztotal = ninf + N * NH + N + N * D1 + N * 2;        // + denoms + accs

    hipLaunchKernelGGL(k_init, dim3(2048), dim3(256), 0, stream, ws, ninf, ztotal);
    hipLaunchKernelGGL(k_node1, dim3((N * NH + 255) / 256), dim3(256), 0, stream,
                       x, W1, as1, ad1, h1, a_s1, a_d1, N);
    hipLaunchKernelGGL(k_edge1_max, dim3((Et + 255) / 256), dim3(256), 0, stream,
                       ei, E, Et, a_s1, a_d1, m1);
    hipLaunchKernelGGL(k_edge1_acc, dim3((Et * NH + 255) / 256), dim3(256), 0, stream,
                       ei, E, Et, a_s1, a_d1, m1, h1, denom1, acc1);
    hipLaunchKernelGGL(k_node2, dim3((N + 255) / 256), dim3(256), 0, stream,
                       acc1, denom1, b1, W2, as2, ad2, h2, a_s2, a_d2, N);
    hipLaunchKernelGGL(k_edge2_max, dim3((Et + 255) / 256), dim3(256), 0, stream,
                       ei, E, Et, a_s2, a_d2, m2);
    hipLaunchKernelGGL(k_edge2_acc, dim3((Et + 255) / 256), dim3(256), 0, stream,
                       ei, E, Et, a_s2, a_d2, m2, h2, denom2, acc2);
    hipLaunchKernelGGL(k_final, dim3((N + 255) / 256), dim3(256), 0, stream,
                       acc2, denom2, b2, out, N);
}

// Round 2
// 782.520 us; speedup vs baseline: 9.9075x; 9.9075x over previous
//
#include <hip/hip_runtime.h>
#include <math.h>

#define F_IN 32
#define NH 8
#define C1 8
#define D1 64
#define NEG 0.2f

// ---------------- CSR build ----------------

__global__ void k_zero_int(int* __restrict__ p, int n) {
    int i = blockIdx.x * blockDim.x + threadIdx.x;
    int stride = gridDim.x * blockDim.x;
    for (; i < n; i += stride) p[i] = 0;
}

__global__ void k_hist(const int* __restrict__ ei, int E, int Et, int* __restrict__ cnt) {
    int i = blockIdx.x * blockDim.x + threadIdx.x;
    if (i >= Et) return;
    int d = (i < E) ? ei[E + i] : (i - E);
    atomicAdd(&cnt[d], 1);
}

// per-block exclusive scan of cnt (256/block), block sums out
__global__ void k_scan_block(const int* __restrict__ cnt, int* __restrict__ ptrtmp,
                             int* __restrict__ bsum, int N) {
    __shared__ int s[256];
    int i = blockIdx.x * 256 + threadIdx.x;
    int v = (i < N) ? cnt[i] : 0;
    s[threadIdx.x] = v;
    __syncthreads();
#pragma unroll
    for (int off = 1; off < 256; off <<= 1) {
        int t = (threadIdx.x >= off) ? s[threadIdx.x - off] : 0;
        __syncthreads();
        s[threadIdx.x] += t;
        __syncthreads();
    }
    ptrtmp[i] = s[threadIdx.x] - v;          // exclusive
    if (threadIdx.x == 255) bsum[blockIdx.x] = s[255];
}

// single-block scan of block sums (nb <= 512) -> exclusive, in place
__global__ void k_scan_bsums(int* __restrict__ bsum, int nb) {
    __shared__ int s[512];
    int t = threadIdx.x;
    s[t] = (t < nb) ? bsum[t] : 0;
    __syncthreads();
#pragma unroll
    for (int off = 1; off < 512; off <<= 1) {
        int v = (t >= off) ? s[t - off] : 0;
        __syncthreads();
        s[t] += v;
        __syncthreads();
    }
    if (t < nb) bsum[t] = (t == 0) ? 0 : s[t - 1];
}

__global__ void k_scan_finalize(const int* __restrict__ ptrtmp, const int* __restrict__ bsum,
                                int* __restrict__ ptr, int* __restrict__ cursor, int N, int Et) {
    int i = blockIdx.x * blockDim.x + threadIdx.x;
    if (i > N) return;
    int v = (i < N) ? (ptrtmp[i] + bsum[i >> 8]) : Et;
    ptr[i] = v;
    if (i < N) cursor[i] = v;
}

__global__ void k_scatter(const int* __restrict__ ei, int E, int Et,
                          int* __restrict__ cursor, int* __restrict__ srcs) {
    int i = blockIdx.x * blockDim.x + threadIdx.x;
    if (i >= Et) return;
    int s, d;
    if (i < E) { s = ei[i]; d = ei[E + i]; } else { s = i - E; d = s; }
    int pos = atomicAdd(&cursor[d], 1);
    srcs[pos] = s;
}

// ---------------- layer-0 node transform ----------------

__global__ void k_node1(const float* __restrict__ x, const float* __restrict__ W1,
                        const float* __restrict__ as1, const float* __restrict__ ad1,
                        float* __restrict__ h1, float* __restrict__ a_s, float* __restrict__ a_d,
                        int N) {
    __shared__ float sW[F_IN * D1];
    __shared__ float sA[2 * D1];
    for (int i = threadIdx.x; i < F_IN * D1; i += blockDim.x) sW[i] = W1[i];
    if (threadIdx.x < 2 * D1)
        sA[threadIdx.x] = (threadIdx.x < D1) ? as1[threadIdx.x] : ad1[threadIdx.x - D1];
    __syncthreads();
    int t = blockIdx.x * blockDim.x + threadIdx.x;
    int n = t >> 3, h = t & 7;
    if (n >= N) return;
    float xr[F_IN];
    const float4* xv = (const float4*)(x + n * F_IN);
#pragma unroll
    for (int k = 0; k < F_IN / 4; ++k) {
        float4 v = xv[k];
        xr[4 * k] = v.x; xr[4 * k + 1] = v.y; xr[4 * k + 2] = v.z; xr[4 * k + 3] = v.w;
    }
    float acc[C1];
#pragma unroll
    for (int c = 0; c < C1; ++c) acc[c] = 0.0f;
#pragma unroll
    for (int k = 0; k < F_IN; ++k) {
        float xk = xr[k];
#pragma unroll
        for (int c = 0; c < C1; ++c) acc[c] = fmaf(xk, sW[k * D1 + h * C1 + c], acc[c]);
    }
    float s_ = 0.0f, d_ = 0.0f;
#pragma unroll
    for (int c = 0; c < C1; ++c) {
        h1[n * D1 + h * C1 + c] = acc[c];
        s_ = fmaf(acc[c], sA[h * C1 + c], s_);
        d_ = fmaf(acc[c], sA[D1 + h * C1 + c], d_);
    }
    a_s[n * NH + h] = s_;
    a_d[n * NH + h] = d_;
}

// ---------------- layer 1: wave per node, lane = (head, channel) ----------------
// online softmax over incoming edges, fully in registers; epilogue fuses
// normalize + b1 + ELU + @W2 + layer-2 attention logits via wave reduction.

__global__ void k_gat1(const int* __restrict__ ptr, const int* __restrict__ srcs,
                       const float* __restrict__ a_s, const float* __restrict__ a_d,
                       const float* __restrict__ h1,
                       const float* __restrict__ b1, const float* __restrict__ W2,
                       const float* __restrict__ as2, const float* __restrict__ ad2,
                       float* __restrict__ h2, float* __restrict__ a_s2o, float* __restrict__ a_d2o,
                       int N) {
    int n = (blockIdx.x * blockDim.x + threadIdx.x) >> 6;
    if (n >= N) return;
    int l = threadIdx.x & 63;
    int h = l >> 3;
    int start = ptr[n], end = ptr[n + 1];
    float ad = a_d[n * NH + h];
    float m = -INFINITY, den = 0.0f, acc = 0.0f;
    for (int idx = start; idx < end; ++idx) {
        int s = srcs[idx];
        float e = a_s[s * NH + h] + ad;
        e = e > 0.0f ? e : NEG * e;
        float mn = fmaxf(m, e);
        float sc = __expf(m - mn);   // m=-inf first iter -> 0
        float ex = __expf(e - mn);
        den = den * sc + ex;
        acc = acc * sc + ex * h1[s * D1 + l];
        m = mn;
    }
    float v = acc / den + b1[l];
    v = v > 0.0f ? v : expm1f(v);    // ELU
    float r0 = v * W2[l * 2 + 0];
    float r1 = v * W2[l * 2 + 1];
#pragma unroll
    for (int off = 32; off; off >>= 1) {
        r0 += __shfl_xor(r0, off, 64);
        r1 += __shfl_xor(r1, off, 64);
    }
    if (l == 0) {
        h2[n * 2 + 0] = r0;
        h2[n * 2 + 1] = r1;
        a_s2o[n] = r0 * as2[0] + r1 * as2[1];
        a_d2o[n] = r0 * ad2[0] + r1 * ad2[1];
    }
}

// ---------------- layer 2: wave per node, lanes stride edges ----------------

__global__ void k_gat2(const int* __restrict__ ptr, const int* __restrict__ srcs,
                       const float* __restrict__ a_s2, const float* __restrict__ a_d2,
                       const float* __restrict__ h2, const float* __restrict__ b2,
                       float* __restrict__ out, int N) {
    int n = (blockIdx.x * blockDim.x + threadIdx.x) >> 6;
    if (n >= N) return;
    int l = threadIdx.x & 63;
    int start = ptr[n], end = ptr[n + 1];
    float ad = a_d2[n];
    float m = -INFINITY, den = 0.0f, a0 = 0.0f, a1 = 0.0f;
    for (int idx = start + l; idx < end; idx += 64) {
        int s = srcs[idx];
        float e = a_s2[s] + ad;
        e = e > 0.0f ? e : NEG * e;
        float mn = fmaxf(m, e);
        float sc = __expf(m - mn);
        float ex = __expf(e - mn);
        den = den * sc + ex;
        a0 = a0 * sc + ex * h2[s * 2 + 0];
        a1 = a1 * sc + ex * h2[s * 2 + 1];
        m = mn;
    }
    // butterfly combine of online-softmax states
#pragma unroll
    for (int off = 32; off; off >>= 1) {
        float m2 = __shfl_xor(m, off, 64);
        float d2 = __shfl_xor(den, off, 64);
        float b0 = __shfl_xor(a0, off, 64);
        float b1_ = __shfl_xor(a1, off, 64);
        float mn = fmaxf(m, m2);
        float s1 = (m == mn) ? 1.0f : __expf(m - mn);    // guard -inf - -inf
        float s2 = (m2 == mn) ? 1.0f : __expf(m2 - mn);
        den = den * s1 + d2 * s2;
        a0 = a0 * s1 + b0 * s2;
        a1 = a1 * s1 + b1_ * s2;
        m = mn;
    }
    if (l == 0) {
        float o0 = a0 / den + b2[0];
        float o1 = a1 / den + b2[1];
        float mx = fmaxf(o0, o1);
        float lse = mx + logf(__expf(o0 - mx) + __expf(o1 - mx));
        out[n * 2 + 0] = o0 - lse;
        out[n * 2 + 1] = o1 - lse;
    }
}

extern "C" void kernel_launch(void* const* d_in, const int* in_sizes, int n_in,
                              void* d_out, int out_size, void* d_ws, size_t ws_size,
                              hipStream_t stream) {
    const float* x   = (const float*)d_in[0];
    const int*   ei  = (const int*)d_in[1];
    const float* W1  = (const float*)d_in[2];
    const float* as1 = (const float*)d_in[3];
    const float* ad1 = (const float*)d_in[4];
    const float* b1  = (const float*)d_in[5];
    const float* W2  = (const float*)d_in[6];
    const float* as2 = (const float*)d_in[7];
    const float* ad2 = (const float*)d_in[8];
    const float* b2  = (const float*)d_in[9];
    float* out = (float*)d_out;

    const int N  = in_sizes[0] / F_IN;   // 100000
    const int E  = in_sizes[1] / 2;      // 3200000
    const int Et = E + N;
    const int nb = (N + 255) / 256;      // scan blocks (391 <= 512)

    // ---- workspace layout ----
    char* p = (char*)d_ws;
    float* h1   = (float*)p; p += (size_t)N * D1 * 4;
    float* a_s1 = (float*)p; p += (size_t)N * NH * 4;
    float* a_d1 = (float*)p; p += (size_t)N * NH * 4;
    float* h2   = (float*)p; p += (size_t)N * 2 * 4;
    float* a_s2 = (float*)p; p += (size_t)N * 4;
    float* a_d2 = (float*)p; p += (size_t)N * 4;
    int* cnt    = (int*)p;   p += (size_t)N * 4;
    int* ptrtmp = (int*)p;   p += (size_t)nb * 256 * 4;
    int* bsum   = (int*)p;   p += (size_t)nb * 4;
    int* ptr    = (int*)p;   p += (size_t)(N + 1) * 4;
    int* cursor = (int*)p;   p += (size_t)N * 4;
    int* srcs   = (int*)p;   p += (size_t)Et * 4;

    // ---- CSR build ----
    hipLaunchKernelGGL(k_zero_int, dim3(512), dim3(256), 0, stream, cnt, N);
    hipLaunchKernelGGL(k_hist, dim3((Et + 255) / 256), dim3(256), 0, stream, ei, E, Et, cnt);
    hipLaunchKernelGGL(k_scan_block, dim3(nb), dim3(256), 0, stream, cnt, ptrtmp, bsum, N);
    hipLaunchKernelGGL(k_scan_bsums, dim3(1), dim3(512), 0, stream, bsum, nb);
    hipLaunchKernelGGL(k_scan_finalize, dim3((N + 256) / 256), dim3(256), 0, stream,
                       ptrtmp, bsum, ptr, cursor, N, Et);
    hipLaunchKernelGGL(k_scatter, dim3((Et + 255) / 256), dim3(256), 0, stream,
                       ei, E, Et, cursor, srcs);

    // ---- node transform ----
    hipLaunchKernelGGL(k_node1, dim3((N * NH + 255) / 256), dim3(256), 0, stream,
                       x, W1, as1, ad1, h1, a_s1, a_d1, N);

    // ---- layer 1 (wave per node) ----
    hipLaunchKernelGGL(k_gat1, dim3((N + 3) / 4), dim3(256), 0, stream,
                       ptr, srcs, a_s1, a_d1, h1, b1, W2, as2, ad2, h2, a_s2, a_d2, N);

    // ---- layer 2 (wave per node) ----
    hipLaunchKernelGGL(k_gat2, dim3((N + 3) / 4), dim3(256), 0, stream,
                       ptr, srcs, a_s2, a_d2, h2, b2, out, N);
}

// Round 3
// 609.533 us; speedup vs baseline: 12.7193x; 1.2838x over previous
//
#include <hip/hip_runtime.h>
#include <math.h>

#define F_IN 32
#define NH 8
#define C1 8
#define D1 64
#define NEG 0.2f
#define LOG2E 1.44269504088896f
#define SHBIAS (-20.0f * LOG2E)   // fixed softmax shift (shift-invariant, avoids overflow)

// ---------------- CSR build ----------------

__global__ void k_zero_int(int* __restrict__ p, int n) {
    int i = blockIdx.x * blockDim.x + threadIdx.x;
    int stride = gridDim.x * blockDim.x;
    for (; i < n; i += stride) p[i] = 0;
}

__global__ void k_hist(const int* __restrict__ ei, int E, int Et, int* __restrict__ cnt) {
    int i = blockIdx.x * blockDim.x + threadIdx.x;
    if (i >= Et) return;
    int d = (i < E) ? ei[E + i] : (i - E);
    atomicAdd(&cnt[d], 1);
}

__global__ void k_scan_block(const int* __restrict__ cnt, int* __restrict__ ptrtmp,
                             int* __restrict__ bsum, int N) {
    __shared__ int s[256];
    int i = blockIdx.x * 256 + threadIdx.x;
    int v = (i < N) ? cnt[i] : 0;
    s[threadIdx.x] = v;
    __syncthreads();
#pragma unroll
    for (int off = 1; off < 256; off <<= 1) {
        int t = (threadIdx.x >= off) ? s[threadIdx.x - off] : 0;
        __syncthreads();
        s[threadIdx.x] += t;
        __syncthreads();
    }
    ptrtmp[i] = s[threadIdx.x] - v;
    if (threadIdx.x == 255) bsum[blockIdx.x] = s[255];
}

__global__ void k_scan_bsums(int* __restrict__ bsum, int nb) {
    __shared__ int s[512];
    int t = threadIdx.x;
    s[t] = (t < nb) ? bsum[t] : 0;
    __syncthreads();
#pragma unroll
    for (int off = 1; off < 512; off <<= 1) {
        int v = (t >= off) ? s[t - off] : 0;
        __syncthreads();
        s[t] += v;
        __syncthreads();
    }
    if (t < nb) bsum[t] = (t == 0) ? 0 : s[t - 1];
}

__global__ void k_scan_finalize(const int* __restrict__ ptrtmp, const int* __restrict__ bsum,
                                int* __restrict__ ptr, int* __restrict__ cursor, int N, int Et) {
    int i = blockIdx.x * blockDim.x + threadIdx.x;
    if (i > N) return;
    int v = (i < N) ? (ptrtmp[i] + bsum[i >> 8]) : Et;
    ptr[i] = v;
    if (i < N) cursor[i] = v;
}

__global__ void k_scatter(const int* __restrict__ ei, int E, int Et,
                          int* __restrict__ cursor, int* __restrict__ srcs) {
    int i = blockIdx.x * blockDim.x + threadIdx.x;
    if (i >= Et) return;
    int s, d;
    if (i < E) { s = ei[i]; d = ei[E + i]; } else { s = i - E; d = s; }
    int pos = atomicAdd(&cursor[d], 1);
    srcs[pos] = s;
}

// ---------------- layer-0 node transform ----------------

__global__ void k_node1(const float* __restrict__ x, const float* __restrict__ W1,
                        const float* __restrict__ as1, const float* __restrict__ ad1,
                        float* __restrict__ h1, float* __restrict__ a_s, float* __restrict__ a_d,
                        int N) {
    __shared__ float sW[F_IN * D1];
    __shared__ float sA[2 * D1];
    for (int i = threadIdx.x; i < F_IN * D1; i += blockDim.x) sW[i] = W1[i];
    if (threadIdx.x < 2 * D1)
        sA[threadIdx.x] = (threadIdx.x < D1) ? as1[threadIdx.x] : ad1[threadIdx.x - D1];
    __syncthreads();
    int t = blockIdx.x * blockDim.x + threadIdx.x;
    int n = t >> 3, h = t & 7;
    if (n >= N) return;
    float xr[F_IN];
    const float4* xv = (const float4*)(x + n * F_IN);
#pragma unroll
    for (int k = 0; k < F_IN / 4; ++k) {
        float4 v = xv[k];
        xr[4 * k] = v.x; xr[4 * k + 1] = v.y; xr[4 * k + 2] = v.z; xr[4 * k + 3] = v.w;
    }
    float acc[C1];
#pragma unroll
    for (int c = 0; c < C1; ++c) acc[c] = 0.0f;
#pragma unroll
    for (int k = 0; k < F_IN; ++k) {
        float xk = xr[k];
#pragma unroll
        for (int c = 0; c < C1; ++c) acc[c] = fmaf(xk, sW[k * D1 + h * C1 + c], acc[c]);
    }
    float s_ = 0.0f, d_ = 0.0f;
#pragma unroll
    for (int c = 0; c < C1; ++c) {
        h1[n * D1 + h * C1 + c] = acc[c];
        s_ = fmaf(acc[c], sA[h * C1 + c], s_);
        d_ = fmaf(acc[c], sA[D1 + h * C1 + c], d_);
    }
    a_s[n * NH + h] = s_;
    a_d[n * NH + h] = d_;
}

// ---------------- layer 1: wave per node, lane = (head, channel) ----------------
// fixed-shift softmax (no running max -> no serial rescale chain), 4x unrolled
// gathers for memory-level parallelism. Epilogue fuses normalize + b1 + ELU +
// @W2 + layer-2 attention logits via wave reduction.

__device__ __forceinline__ float lrelu(float e) { return e > 0.0f ? e : NEG * e; }

__global__ void k_gat1(const int* __restrict__ ptr, const int* __restrict__ srcs,
                       const float* __restrict__ a_s, const float* __restrict__ a_d,
                       const float* __restrict__ h1,
                       const float* __restrict__ b1, const float* __restrict__ W2,
                       const float* __restrict__ as2, const float* __restrict__ ad2,
                       float* __restrict__ h2, float* __restrict__ a_s2o, float* __restrict__ a_d2o,
                       int N) {
    int n = (blockIdx.x * blockDim.x + threadIdx.x) >> 6;
    if (n >= N) return;
    int l = threadIdx.x & 63;
    int h = l >> 3;
    int start = ptr[n], end = ptr[n + 1];
    float ad = a_d[n * NH + h];
    float den = 0.0f, acc = 0.0f;
    int idx = start;
    for (; idx + 4 <= end; idx += 4) {
        int s0 = srcs[idx + 0], s1 = srcs[idx + 1], s2 = srcs[idx + 2], s3 = srcs[idx + 3];
        float as0 = a_s[s0 * NH + h], as1 = a_s[s1 * NH + h];
        float as2_ = a_s[s2 * NH + h], as3 = a_s[s3 * NH + h];
        float g0 = h1[s0 * D1 + l], g1 = h1[s1 * D1 + l];
        float g2 = h1[s2 * D1 + l], g3 = h1[s3 * D1 + l];
        float x0 = exp2f(fmaf(lrelu(as0 + ad), LOG2E, SHBIAS));
        float x1 = exp2f(fmaf(lrelu(as1 + ad), LOG2E, SHBIAS));
        float x2 = exp2f(fmaf(lrelu(as2_ + ad), LOG2E, SHBIAS));
        float x3 = exp2f(fmaf(lrelu(as3 + ad), LOG2E, SHBIAS));
        den += (x0 + x1) + (x2 + x3);
        acc = fmaf(x0, g0, acc);
        acc = fmaf(x1, g1, acc);
        acc = fmaf(x2, g2, acc);
        acc = fmaf(x3, g3, acc);
    }
    for (; idx < end; ++idx) {
        int s = srcs[idx];
        float ex = exp2f(fmaf(lrelu(a_s[s * NH + h] + ad), LOG2E, SHBIAS));
        den += ex;
        acc = fmaf(ex, h1[s * D1 + l], acc);
    }
    float v = acc / den + b1[l];
    v = v > 0.0f ? v : expm1f(v);    // ELU
    float r0 = v * W2[l * 2 + 0];
    float r1 = v * W2[l * 2 + 1];
#pragma unroll
    for (int off = 32; off; off >>= 1) {
        r0 += __shfl_xor(r0, off, 64);
        r1 += __shfl_xor(r1, off, 64);
    }
    if (l == 0) {
        h2[n * 2 + 0] = r0;
        h2[n * 2 + 1] = r1;
        a_s2o[n] = r0 * as2[0] + r1 * as2[1];
        a_d2o[n] = r0 * ad2[0] + r1 * ad2[1];
    }
}

// ---------------- layer 2: wave per node, lanes stride edges ----------------

__global__ void k_gat2(const int* __restrict__ ptr, const int* __restrict__ srcs,
                       const float* __restrict__ a_s2, const float* __restrict__ a_d2,
                       const float* __restrict__ h2, const float* __restrict__ b2,
                       float* __restrict__ out, int N) {
    int n = (blockIdx.x * blockDim.x + threadIdx.x) >> 6;
    if (n >= N) return;
    int l = threadIdx.x & 63;
    int start = ptr[n], end = ptr[n + 1];
    float ad = a_d2[n];
    float den = 0.0f, a0 = 0.0f, a1 = 0.0f;
    for (int idx = start + l; idx < end; idx += 64) {
        int s = srcs[idx];
        float ex = exp2f(fmaf(lrelu(a_s2[s] + ad), LOG2E, SHBIAS));
        float2 hv = *(const float2*)(h2 + s * 2);
        den += ex;
        a0 = fmaf(ex, hv.x, a0);
        a1 = fmaf(ex, hv.y, a1);
    }
#pragma unroll
    for (int off = 32; off; off >>= 1) {
        den += __shfl_xor(den, off, 64);
        a0  += __shfl_xor(a0, off, 64);
        a1  += __shfl_xor(a1, off, 64);
    }
    if (l == 0) {
        float inv = 1.0f / den;
        float o0 = a0 * inv + b2[0];
        float o1 = a1 * inv + b2[1];
        float mx = fmaxf(o0, o1);
        float lse = mx + logf(__expf(o0 - mx) + __expf(o1 - mx));
        out[n * 2 + 0] = o0 - lse;
        out[n * 2 + 1] = o1 - lse;
    }
}

extern "C" void kernel_launch(void* const* d_in, const int* in_sizes, int n_in,
                              void* d_out, int out_size, void* d_ws, size_t ws_size,
                              hipStream_t stream) {
    const float* x   = (const float*)d_in[0];
    const int*   ei  = (const int*)d_in[1];
    const float* W1  = (const float*)d_in[2];
    const float* as1 = (const float*)d_in[3];
    const float* ad1 = (const float*)d_in[4];
    const float* b1  = (const float*)d_in[5];
    const float* W2  = (const float*)d_in[6];
    const float* as2 = (const float*)d_in[7];
    const float* ad2 = (const float*)d_in[8];
    const float* b2  = (const float*)d_in[9];
    float* out = (float*)d_out;

    const int N  = in_sizes[0] / F_IN;   // 100000
    const int E  = in_sizes[1] / 2;      // 3200000
    const int Et = E + N;
    const int nb = (N + 255) / 256;

    char* p = (char*)d_ws;
    float* h1   = (float*)p; p += (size_t)N * D1 * 4;
    float* a_s1 = (float*)p; p += (size_t)N * NH * 4;
    float* a_d1 = (float*)p; p += (size_t)N * NH * 4;
    float* h2   = (float*)p; p += (size_t)N * 2 * 4;
    float* a_s2 = (float*)p; p += (size_t)N * 4;
    float* a_d2 = (float*)p; p += (size_t)N * 4;
    int* cnt    = (int*)p;   p += (size_t)N * 4;
    int* ptrtmp = (int*)p;   p += (size_t)nb * 256 * 4;
    int* bsum   = (int*)p;   p += (size_t)nb * 4;
    int* ptr    = (int*)p;   p += (size_t)(N + 1) * 4;
    int* cursor = (int*)p;   p += (size_t)N * 4;
    int* srcs   = (int*)p;   p += (size_t)Et * 4;

    hipLaunchKernelGGL(k_zero_int, dim3(512), dim3(256), 0, stream, cnt, N);
    hipLaunchKernelGGL(k_hist, dim3((Et + 255) / 256), dim3(256), 0, stream, ei, E, Et, cnt);
    hipLaunchKernelGGL(k_scan_block, dim3(nb), dim3(256), 0, stream, cnt, ptrtmp, bsum, N);
    hipLaunchKernelGGL(k_scan_bsums, dim3(1), dim3(512), 0, stream, bsum, nb);
    hipLaunchKernelGGL(k_scan_finalize, dim3((N + 256) / 256), dim3(256), 0, stream,
                       ptrtmp, bsum, ptr, cursor, N, Et);
    hipLaunchKernelGGL(k_scatter, dim3((Et + 255) / 256), dim3(256), 0, stream,
                       ei, E, Et, cursor, srcs);

    hipLaunchKernelGGL(k_node1, dim3((N * NH + 255) / 256), dim3(256), 0, stream,
                       x, W1, as1, ad1, h1, a_s1, a_d1, N);

    hipLaunchKernelGGL(k_gat1, dim3((N + 3) / 4), dim3(256), 0, stream,
                       ptr, srcs, a_s1, a_d1, h1, b1, W2, as2, ad2, h2, a_s2, a_d2, N);

    hipLaunchKernelGGL(k_gat2, dim3((N + 3) / 4), dim3(256), 0, stream,
                       ptr, srcs, a_s2, a_d2, h2, b2, out, N);
}

// Round 4
// 487.012 us; speedup vs baseline: 15.9192x; 1.2516x over previous
//
#include <hip/hip_runtime.h>
#include <math.h>

#define F_IN 32
#define NH 8
#define C1 8
#define D1 64
#define NEG 0.2f
#define LOG2E 1.44269504088896f
#define SHBIAS (-20.0f * LOG2E)   // fixed softmax shift (shift-invariant, avoids overflow)
#define NR 8                      // scatter dst-ranges (match 8 XCDs)
#define CHUNK 8192                // edges per scatter block

// ---------------- CSR build ----------------

__global__ void k_zero_int(int* __restrict__ p, int n) {
    int i = blockIdx.x * blockDim.x + threadIdx.x;
    int stride = gridDim.x * blockDim.x;
    for (; i < n; i += stride) p[i] = 0;
}

__global__ void k_hist(const int* __restrict__ ei, int E, int Et, int* __restrict__ cnt) {
    int i = blockIdx.x * blockDim.x + threadIdx.x;
    if (i >= Et) return;
    int d = (i < E) ? ei[E + i] : (i - E);
    atomicAdd(&cnt[d], 1);
}

__global__ void k_scan_block(const int* __restrict__ cnt, int* __restrict__ ptrtmp,
                             int* __restrict__ bsum, int N) {
    __shared__ int s[256];
    int i = blockIdx.x * 256 + threadIdx.x;
    int v = (i < N) ? cnt[i] : 0;
    s[threadIdx.x] = v;
    __syncthreads();
#pragma unroll
    for (int off = 1; off < 256; off <<= 1) {
        int t = (threadIdx.x >= off) ? s[threadIdx.x - off] : 0;
        __syncthreads();
        s[threadIdx.x] += t;
        __syncthreads();
    }
    ptrtmp[i] = s[threadIdx.x] - v;
    if (threadIdx.x == 255) bsum[blockIdx.x] = s[255];
}

__global__ void k_scan_bsums(int* __restrict__ bsum, int nb) {
    __shared__ int s[512];
    int t = threadIdx.x;
    s[t] = (t < nb) ? bsum[t] : 0;
    __syncthreads();
#pragma unroll
    for (int off = 1; off < 512; off <<= 1) {
        int v = (t >= off) ? s[t - off] : 0;
        __syncthreads();
        s[t] += v;
        __syncthreads();
    }
    if (t < nb) bsum[t] = (t == 0) ? 0 : s[t - 1];
}

__global__ void k_scan_finalize(const int* __restrict__ ptrtmp, const int* __restrict__ bsum,
                                int* __restrict__ ptr, int* __restrict__ cursor, int N, int Et) {
    int i = blockIdx.x * blockDim.x + threadIdx.x;
    if (i > N) return;
    int v = (i < N) ? (ptrtmp[i] + bsum[i >> 8]) : Et;
    ptr[i] = v;
    if (i < N) cursor[i] = v;
}

// range-partitioned scatter: block b -> dst range (b&7) [XCD-affine under
// round-robin blockIdx->XCD], edge chunk (b>>3). Confines srcs writes to a
// ~1.65MB window per range so L2 lines fill before eviction.
__global__ void k_scatter_r(const int* __restrict__ ei, int E, int Et, int rngSize,
                            int* __restrict__ cursor, int* __restrict__ srcs) {
    int range = blockIdx.x & (NR - 1);
    int chunk = blockIdx.x / NR;
    int lo = range * rngSize, hi = lo + rngSize;
    int base = chunk * CHUNK;
    int stop = base + CHUNK; if (stop > Et) stop = Et;
    for (int i = base + threadIdx.x; i < stop; i += blockDim.x) {
        int d = (i < E) ? ei[E + i] : (i - E);
        if (d >= lo && d < hi) {
            int s = (i < E) ? ei[i] : d;
            int pos = atomicAdd(&cursor[d], 1);
            srcs[pos] = s;
        }
    }
}

// ---------------- layer-0 node transform ----------------

__global__ void k_node1(const float* __restrict__ x, const float* __restrict__ W1,
                        const float* __restrict__ as1, const float* __restrict__ ad1,
                        float* __restrict__ h1, float* __restrict__ a_s, float* __restrict__ a_d,
                        int N) {
    __shared__ float sW[F_IN * D1];
    __shared__ float sA[2 * D1];
    for (int i = threadIdx.x; i < F_IN * D1; i += blockDim.x) sW[i] = W1[i];
    if (threadIdx.x < 2 * D1)
        sA[threadIdx.x] = (threadIdx.x < D1) ? as1[threadIdx.x] : ad1[threadIdx.x - D1];
    __syncthreads();
    int t = blockIdx.x * blockDim.x + threadIdx.x;
    int n = t >> 3, h = t & 7;
    if (n >= N) return;
    float xr[F_IN];
    const float4* xv = (const float4*)(x + n * F_IN);
#pragma unroll
    for (int k = 0; k < F_IN / 4; ++k) {
        float4 v = xv[k];
        xr[4 * k] = v.x; xr[4 * k + 1] = v.y; xr[4 * k + 2] = v.z; xr[4 * k + 3] = v.w;
    }
    float acc[C1];
#pragma unroll
    for (int c = 0; c < C1; ++c) acc[c] = 0.0f;
#pragma unroll
    for (int k = 0; k < F_IN; ++k) {
        float xk = xr[k];
#pragma unroll
        for (int c = 0; c < C1; ++c) acc[c] = fmaf(xk, sW[k * D1 + h * C1 + c], acc[c]);
    }
    float s_ = 0.0f, d_ = 0.0f;
#pragma unroll
    for (int c = 0; c < C1; ++c) {
        h1[n * D1 + h * C1 + c] = acc[c];
        s_ = fmaf(acc[c], sA[h * C1 + c], s_);
        d_ = fmaf(acc[c], sA[D1 + h * C1 + c], d_);
    }
    a_s[n * NH + h] = s_;
    a_d[n * NH + h] = d_;
}

// ---------------- layer 1: wave per node, lane = (head, channel) ----------------

__device__ __forceinline__ float lrelu(float e) { return e > 0.0f ? e : NEG * e; }

__global__ void k_gat1(const int* __restrict__ ptr, const int* __restrict__ srcs,
                       const float* __restrict__ a_s, const float* __restrict__ a_d,
                       const float* __restrict__ h1,
                       const float* __restrict__ b1, const float* __restrict__ W2,
                       const float* __restrict__ as2, const float* __restrict__ ad2,
                       float* __restrict__ h2, float* __restrict__ a_s2o, float* __restrict__ a_d2o,
                       int N) {
    int n = (blockIdx.x * blockDim.x + threadIdx.x) >> 6;
    if (n >= N) return;
    int l = threadIdx.x & 63;
    int h = l >> 3;
    int start = ptr[n], end = ptr[n + 1];
    float ad = a_d[n * NH + h];
    float den = 0.0f, acc = 0.0f;
    int idx = start;
    for (; idx + 4 <= end; idx += 4) {
        int s0 = srcs[idx + 0], s1 = srcs[idx + 1], s2 = srcs[idx + 2], s3 = srcs[idx + 3];
        float as0 = a_s[s0 * NH + h], as1 = a_s[s1 * NH + h];
        float as2_ = a_s[s2 * NH + h], as3 = a_s[s3 * NH + h];
        float g0 = h1[s0 * D1 + l], g1 = h1[s1 * D1 + l];
        float g2 = h1[s2 * D1 + l], g3 = h1[s3 * D1 + l];
        float x0 = exp2f(fmaf(lrelu(as0 + ad), LOG2E, SHBIAS));
        float x1 = exp2f(fmaf(lrelu(as1 + ad), LOG2E, SHBIAS));
        float x2 = exp2f(fmaf(lrelu(as2_ + ad), LOG2E, SHBIAS));
        float x3 = exp2f(fmaf(lrelu(as3 + ad), LOG2E, SHBIAS));
        den += (x0 + x1) + (x2 + x3);
        acc = fmaf(x0, g0, acc);
        acc = fmaf(x1, g1, acc);
        acc = fmaf(x2, g2, acc);
        acc = fmaf(x3, g3, acc);
    }
    for (; idx < end; ++idx) {
        int s = srcs[idx];
        float ex = exp2f(fmaf(lrelu(a_s[s * NH + h] + ad), LOG2E, SHBIAS));
        den += ex;
        acc = fmaf(ex, h1[s * D1 + l], acc);
    }
    float v = acc / den + b1[l];
    v = v > 0.0f ? v : expm1f(v);    // ELU
    float r0 = v * W2[l * 2 + 0];
    float r1 = v * W2[l * 2 + 1];
#pragma unroll
    for (int off = 32; off; off >>= 1) {
        r0 += __shfl_xor(r0, off, 64);
        r1 += __shfl_xor(r1, off, 64);
    }
    if (l == 0) {
        h2[n * 2 + 0] = r0;
        h2[n * 2 + 1] = r1;
        a_s2o[n] = r0 * as2[0] + r1 * as2[1];
        a_d2o[n] = r0 * ad2[0] + r1 * ad2[1];
    }
}

// ---------------- layer 2: 16 lanes per node (avg degree ~33) ----------------

__global__ void k_gat2(const int* __restrict__ ptr, const int* __restrict__ srcs,
                       const float* __restrict__ a_s2, const float* __restrict__ a_d2,
                       const float* __restrict__ h2, const float* __restrict__ b2,
                       float* __restrict__ out, int N) {
    int t = blockIdx.x * blockDim.x + threadIdx.x;
    int n = t >> 4;
    if (n >= N) return;
    int l = threadIdx.x & 15;
    int start = ptr[n], end = ptr[n + 1];
    float ad = a_d2[n];
    float den = 0.0f, a0 = 0.0f, a1 = 0.0f;
    for (int idx = start + l; idx < end; idx += 16) {
        int s = srcs[idx];
        float ex = exp2f(fmaf(lrelu(a_s2[s] + ad), LOG2E, SHBIAS));
        float2 hv = *(const float2*)(h2 + s * 2);
        den += ex;
        a0 = fmaf(ex, hv.x, a0);
        a1 = fmaf(ex, hv.y, a1);
    }
#pragma unroll
    for (int off = 8; off; off >>= 1) {
        den += __shfl_xor(den, off, 16);
        a0  += __shfl_xor(a0, off, 16);
        a1  += __shfl_xor(a1, off, 16);
    }
    if (l == 0) {
        float inv = 1.0f / den;
        float o0 = a0 * inv + b2[0];
        float o1 = a1 * inv + b2[1];
        float mx = fmaxf(o0, o1);
        float lse = mx + logf(__expf(o0 - mx) + __expf(o1 - mx));
        out[n * 2 + 0] = o0 - lse;
        out[n * 2 + 1] = o1 - lse;
    }
}

extern "C" void kernel_launch(void* const* d_in, const int* in_sizes, int n_in,
                              void* d_out, int out_size, void* d_ws, size_t ws_size,
                              hipStream_t stream) {
    const float* x   = (const float*)d_in[0];
    const int*   ei  = (const int*)d_in[1];
    const float* W1  = (const float*)d_in[2];
    const float* as1 = (const float*)d_in[3];
    const float* ad1 = (const float*)d_in[4];
    const float* b1  = (const float*)d_in[5];
    const float* W2  = (const float*)d_in[6];
    const float* as2 = (const float*)d_in[7];
    const float* ad2 = (const float*)d_in[8];
    const float* b2  = (const float*)d_in[9];
    float* out = (float*)d_out;

    const int N  = in_sizes[0] / F_IN;   // 100000
    const int E  = in_sizes[1] / 2;      // 3200000
    const int Et = E + N;
    const int nb = (N + 255) / 256;
    const int rngSize = (N + NR - 1) / NR;

    char* p = (char*)d_ws;
    float* h1   = (float*)p; p += (size_t)N * D1 * 4;
    float* a_s1 = (float*)p; p += (size_t)N * NH * 4;
    float* a_d1 = (float*)p; p += (size_t)N * NH * 4;
    float* h2   = (float*)p; p += (size_t)N * 2 * 4;
    float* a_s2 = (float*)p; p += (size_t)N * 4;
    float* a_d2 = (float*)p; p += (size_t)N * 4;
    int* cnt    = (int*)p;   p += (size_t)N * 4;
    int* ptrtmp = (int*)p;   p += (size_t)nb * 256 * 4;
    int* bsum   = (int*)p;   p += (size_t)nb * 4;
    int* ptr    = (int*)p;   p += (size_t)(N + 1) * 4;
    int* cursor = (int*)p;   p += (size_t)N * 4;
    int* srcs   = (int*)p;   p += (size_t)Et * 4;

    hipLaunchKernelGGL(k_zero_int, dim3(512), dim3(256), 0, stream, cnt, N);
    hipLaunchKernelGGL(k_hist, dim3((Et + 255) / 256), dim3(256), 0, stream, ei, E, Et, cnt);
    hipLaunchKernelGGL(k_scan_block, dim3(nb), dim3(256), 0, stream, cnt, ptrtmp, bsum, N);
    hipLaunchKernelGGL(k_scan_bsums, dim3(1), dim3(512), 0, stream, bsum, nb);
    hipLaunchKernelGGL(k_scan_finalize, dim3((N + 256) / 256), dim3(256), 0, stream,
                       ptrtmp, bsum, ptr, cursor, N, Et);

    const int nchunks = (Et + CHUNK - 1) / CHUNK;
    hipLaunchKernelGGL(k_scatter_r, dim3(nchunks * NR), dim3(256), 0, stream,
                       ei, E, Et, rngSize, cursor, srcs);

    hipLaunchKernelGGL(k_node1, dim3((N * NH + 255) / 256), dim3(256), 0, stream,
                       x, W1, as1, ad1, h1, a_s1, a_d1, N);

    hipLaunchKernelGGL(k_gat1, dim3((N + 3) / 4), dim3(256), 0, stream,
                       ptr, srcs, a_s1, a_d1, h1, b1, W2, as2, ad2, h2, a_s2, a_d2, N);

    hipLaunchKernelGGL(k_gat2, dim3((N * 16 + 255) / 256), dim3(256), 0, stream,
                       ptr, srcs, a_s2, a_d2, h2, b2, out, N);
}

// Round 5
// 472.117 us; speedup vs baseline: 16.4214x; 1.0315x over previous
//
#include <hip/hip_runtime.h>
#include <math.h>

#define F_IN 32
#define NH 8
#define C1 8
#define D1 64
#define NEG 0.2f
#define LOG2E 1.44269504088896f
#define SHBIAS (-20.0f * LOG2E)   // fixed softmax shift (shift-invariant, avoids overflow)
#define NR 8                      // scatter dst-ranges (match 8 XCDs)
#define CHUNK 8192                // edges per scatter block

// ---------------- CSR build ----------------

__global__ void k_zero_int(int* __restrict__ p, int n) {
    int i = blockIdx.x * blockDim.x + threadIdx.x;
    int stride = gridDim.x * blockDim.x;
    for (; i < n; i += stride) p[i] = 0;
}

__global__ void k_hist(const int* __restrict__ ei, int E, int Et, int* __restrict__ cnt) {
    int i = blockIdx.x * blockDim.x + threadIdx.x;
    if (i >= Et) return;
    int d = (i < E) ? ei[E + i] : (i - E);
    atomicAdd(&cnt[d], 1);
}

__global__ void k_scan_block(const int* __restrict__ cnt, int* __restrict__ ptrtmp,
                             int* __restrict__ bsum, int N) {
    __shared__ int s[256];
    int i = blockIdx.x * 256 + threadIdx.x;
    int v = (i < N) ? cnt[i] : 0;
    s[threadIdx.x] = v;
    __syncthreads();
#pragma unroll
    for (int off = 1; off < 256; off <<= 1) {
        int t = (threadIdx.x >= off) ? s[threadIdx.x - off] : 0;
        __syncthreads();
        s[threadIdx.x] += t;
        __syncthreads();
    }
    ptrtmp[i] = s[threadIdx.x] - v;
    if (threadIdx.x == 255) bsum[blockIdx.x] = s[255];
}

__global__ void k_scan_bsums(int* __restrict__ bsum, int nb) {
    __shared__ int s[512];
    int t = threadIdx.x;
    s[t] = (t < nb) ? bsum[t] : 0;
    __syncthreads();
#pragma unroll
    for (int off = 1; off < 512; off <<= 1) {
        int v = (t >= off) ? s[t - off] : 0;
        __syncthreads();
        s[t] += v;
        __syncthreads();
    }
    if (t < nb) bsum[t] = (t == 0) ? 0 : s[t - 1];
}

__global__ void k_scan_finalize(const int* __restrict__ ptrtmp, const int* __restrict__ bsum,
                                int* __restrict__ ptr, int* __restrict__ cursor, int N, int Et) {
    int i = blockIdx.x * blockDim.x + threadIdx.x;
    if (i > N) return;
    int v = (i < N) ? (ptrtmp[i] + bsum[i >> 8]) : Et;
    ptr[i] = v;
    if (i < N) cursor[i] = v;
}

// range-partitioned scatter: confines srcs writes to ~1.65MB window per range
// so L2 lines fill before eviction (fixed the 197MB partial-line write storm).
__global__ void k_scatter_r(const int* __restrict__ ei, int E, int Et, int rngSize,
                            int* __restrict__ cursor, int* __restrict__ srcs) {
    int range = blockIdx.x & (NR - 1);
    int chunk = blockIdx.x / NR;
    int lo = range * rngSize, hi = lo + rngSize;
    int base = chunk * CHUNK;
    int stop = base + CHUNK; if (stop > Et) stop = Et;
    for (int i = base + threadIdx.x; i < stop; i += blockDim.x) {
        int d = (i < E) ? ei[E + i] : (i - E);
        if (d >= lo && d < hi) {
            int s = (i < E) ? ei[i] : d;
            int pos = atomicAdd(&cursor[d], 1);
            srcs[pos] = s;
        }
    }
}

// ---------------- layer-0 node transform ----------------

__global__ void k_node1(const float* __restrict__ x, const float* __restrict__ W1,
                        const float* __restrict__ as1, const float* __restrict__ ad1,
                        float* __restrict__ h1, float* __restrict__ a_s, float* __restrict__ a_d,
                        int N) {
    __shared__ float sW[F_IN * D1];
    __shared__ float sA[2 * D1];
    for (int i = threadIdx.x; i < F_IN * D1; i += blockDim.x) sW[i] = W1[i];
    if (threadIdx.x < 2 * D1)
        sA[threadIdx.x] = (threadIdx.x < D1) ? as1[threadIdx.x] : ad1[threadIdx.x - D1];
    __syncthreads();
    int t = blockIdx.x * blockDim.x + threadIdx.x;
    int n = t >> 3, h = t & 7;
    if (n >= N) return;
    float xr[F_IN];
    const float4* xv = (const float4*)(x + n * F_IN);
#pragma unroll
    for (int k = 0; k < F_IN / 4; ++k) {
        float4 v = xv[k];
        xr[4 * k] = v.x; xr[4 * k + 1] = v.y; xr[4 * k + 2] = v.z; xr[4 * k + 3] = v.w;
    }
    float acc[C1];
#pragma unroll
    for (int c = 0; c < C1; ++c) acc[c] = 0.0f;
#pragma unroll
    for (int k = 0; k < F_IN; ++k) {
        float xk = xr[k];
#pragma unroll
        for (int c = 0; c < C1; ++c) acc[c] = fmaf(xk, sW[k * D1 + h * C1 + c], acc[c]);
    }
    float s_ = 0.0f, d_ = 0.0f;
#pragma unroll
    for (int c = 0; c < C1; ++c) {
        h1[n * D1 + h * C1 + c] = acc[c];
        s_ = fmaf(acc[c], sA[h * C1 + c], s_);
        d_ = fmaf(acc[c], sA[D1 + h * C1 + c], d_);
    }
    a_s[n * NH + h] = s_;
    a_d[n * NH + h] = d_;
}

// ---------------- layer 1: wave per node, transposed logit phase ----------------
// Logit phase lane layout: (edge-slot j = l>>3, head = l&7) -> 8 edges get their
// 64 logits with ONE wave-exp2 (was 8: each was replicated over 8 channel lanes).
// Accumulate phase keeps (head = l>>3, chan = l&7): s_j via readlane (SGPR addr),
// ex[j,h] via ds_bpermute. Tail edges clamp to end-1 (cached row) with ex=0.

__device__ __forceinline__ float lrelu(float e) { return e > 0.0f ? e : NEG * e; }

__global__ void __launch_bounds__(256)
k_gat1(const int* __restrict__ ptr, const int* __restrict__ srcs,
       const float* __restrict__ a_s, const float* __restrict__ a_d,
       const float* __restrict__ h1,
       const float* __restrict__ b1, const float* __restrict__ W2,
       const float* __restrict__ as2, const float* __restrict__ ad2,
       float* __restrict__ h2, float* __restrict__ a_s2o, float* __restrict__ a_d2o,
       int N) {
    int n = (blockIdx.x * blockDim.x + threadIdx.x) >> 6;
    if (n >= N) return;
    int l = threadIdx.x & 63;
    int j = l >> 3;          // edge slot (logit phase)
    int h = l & 7;           // head (logit phase)
    int start = ptr[n], end = ptr[n + 1];
    float ad = a_d[n * NH + h];
    const float* hb = h1 + l;    // lane-fixed offset into h1 rows
    float den = 0.0f, acc = 0.0f;
    for (int base = start; base < end; base += 8) {
        int idxl = base + j;
        bool valid = idxl < end;
        if (!valid) idxl = end - 1;
        int s = srcs[idxl];                         // 8 consecutive ints, group-shared
        float as = a_s[(s << 3) + h];               // 8x32B contiguous segments
        float ex = exp2f(fmaf(lrelu(as + ad), LOG2E, SHBIAS));
        if (!valid) ex = 0.0f;
        den += ex;                                   // per-lane (j,h) partial
        // broadcast the 8 source ids to SGPRs
        int s0 = __builtin_amdgcn_readlane(s, 0),  s1 = __builtin_amdgcn_readlane(s, 8);
        int s2 = __builtin_amdgcn_readlane(s, 16), s3 = __builtin_amdgcn_readlane(s, 24);
        int s4 = __builtin_amdgcn_readlane(s, 32), s5 = __builtin_amdgcn_readlane(s, 40);
        int s6 = __builtin_amdgcn_readlane(s, 48), s7 = __builtin_amdgcn_readlane(s, 56);
        // 8 gathers in flight (tail slots re-read the end-1 row: cache hit)
        float g0 = hb[s0 << 6], g1 = hb[s1 << 6], g2 = hb[s2 << 6], g3 = hb[s3 << 6];
        float g4 = hb[s4 << 6], g5 = hb[s5 << 6], g6 = hb[s6 << 6], g7 = hb[s7 << 6];
        // ex[j0, h=l>>3] lives in lane j0*8 + (l>>3)
        int bl = l >> 3;
        float e0 = __shfl(ex, 0 + bl, 64),  e1 = __shfl(ex, 8 + bl, 64);
        float e2 = __shfl(ex, 16 + bl, 64), e3 = __shfl(ex, 24 + bl, 64);
        float e4 = __shfl(ex, 32 + bl, 64), e5 = __shfl(ex, 40 + bl, 64);
        float e6 = __shfl(ex, 48 + bl, 64), e7 = __shfl(ex, 56 + bl, 64);
        acc = fmaf(e0, g0, acc); acc = fmaf(e1, g1, acc);
        acc = fmaf(e2, g2, acc); acc = fmaf(e3, g3, acc);
        acc = fmaf(e4, g4, acc); acc = fmaf(e5, g5, acc);
        acc = fmaf(e6, g6, acc); acc = fmaf(e7, g7, acc);
    }
    // den: lane holds partial for (j=l>>3, h=l&7); sum over j (bits 3..5)
    den += __shfl_xor(den, 8, 64);
    den += __shfl_xor(den, 16, 64);
    den += __shfl_xor(den, 32, 64);
    den = __shfl(den, l >> 3, 64);   // re-layout: lane l gets den[h = l>>3]
    float v = acc / den + b1[l];
    v = v > 0.0f ? v : expm1f(v);    // ELU
    float r0 = v * W2[l * 2 + 0];
    float r1 = v * W2[l * 2 + 1];
#pragma unroll
    for (int off = 32; off; off >>= 1) {
        r0 += __shfl_xor(r0, off, 64);
        r1 += __shfl_xor(r1, off, 64);
    }
    if (l == 0) {
        h2[n * 2 + 0] = r0;
        h2[n * 2 + 1] = r1;
        a_s2o[n] = r0 * as2[0] + r1 * as2[1];
        a_d2o[n] = r0 * ad2[0] + r1 * ad2[1];
    }
}

// ---------------- layer 2: 16 lanes per node (avg degree ~33) ----------------

__global__ void k_gat2(const int* __restrict__ ptr, const int* __restrict__ srcs,
                       const float* __restrict__ a_s2, const float* __restrict__ a_d2,
                       const float* __restrict__ h2, const float* __restrict__ b2,
                       float* __restrict__ out, int N) {
    int t = blockIdx.x * blockDim.x + threadIdx.x;
    int n = t >> 4;
    if (n >= N) return;
    int l = threadIdx.x & 15;
    int start = ptr[n], end = ptr[n + 1];
    float ad = a_d2[n];
    float den = 0.0f, a0 = 0.0f, a1 = 0.0f;
    for (int idx = start + l; idx < end; idx += 16) {
        int s = srcs[idx];
        float ex = exp2f(fmaf(lrelu(a_s2[s] + ad), LOG2E, SHBIAS));
        float2 hv = *(const float2*)(h2 + s * 2);
        den += ex;
        a0 = fmaf(ex, hv.x, a0);
        a1 = fmaf(ex, hv.y, a1);
    }
#pragma unroll
    for (int off = 8; off; off >>= 1) {
        den += __shfl_xor(den, off, 16);
        a0  += __shfl_xor(a0, off, 16);
        a1  += __shfl_xor(a1, off, 16);
    }
    if (l == 0) {
        float inv = 1.0f / den;
        float o0 = a0 * inv + b2[0];
        float o1 = a1 * inv + b2[1];
        float mx = fmaxf(o0, o1);
        float lse = mx + logf(__expf(o0 - mx) + __expf(o1 - mx));
        out[n * 2 + 0] = o0 - lse;
        out[n * 2 + 1] = o1 - lse;
    }
}

extern "C" void kernel_launch(void* const* d_in, const int* in_sizes, int n_in,
                              void* d_out, int out_size, void* d_ws, size_t ws_size,
                              hipStream_t stream) {
    const float* x   = (const float*)d_in[0];
    const int*   ei  = (const int*)d_in[1];
    const float* W1  = (const float*)d_in[2];
    const float* as1 = (const float*)d_in[3];
    const float* ad1 = (const float*)d_in[4];
    const float* b1  = (const float*)d_in[5];
    const float* W2  = (const float*)d_in[6];
    const float* as2 = (const float*)d_in[7];
    const float* ad2 = (const float*)d_in[8];
    const float* b2  = (const float*)d_in[9];
    float* out = (float*)d_out;

    const int N  = in_sizes[0] / F_IN;   // 100000
    const int E  = in_sizes[1] / 2;      // 3200000
    const int Et = E + N;
    const int nb = (N + 255) / 256;
    const int rngSize = (N + NR - 1) / NR;

    char* p = (char*)d_ws;
    float* h1   = (float*)p; p += (size_t)N * D1 * 4;
    float* a_s1 = (float*)p; p += (size_t)N * NH * 4;
    float* a_d1 = (float*)p; p += (size_t)N * NH * 4;
    float* h2   = (float*)p; p += (size_t)N * 2 * 4;
    float* a_s2 = (float*)p; p += (size_t)N * 4;
    float* a_d2 = (float*)p; p += (size_t)N * 4;
    int* cnt    = (int*)p;   p += (size_t)N * 4;
    int* ptrtmp = (int*)p;   p += (size_t)nb * 256 * 4;
    int* bsum   = (int*)p;   p += (size_t)nb * 4;
    int* ptr    = (int*)p;   p += (size_t)(N + 1) * 4;
    int* cursor = (int*)p;   p += (size_t)N * 4;
    int* srcs   = (int*)p;   p += (size_t)Et * 4;

    hipLaunchKernelGGL(k_zero_int, dim3(512), dim3(256), 0, stream, cnt, N);
    hipLaunchKernelGGL(k_hist, dim3((Et + 255) / 256), dim3(256), 0, stream, ei, E, Et, cnt);
    hipLaunchKernelGGL(k_scan_block, dim3(nb), dim3(256), 0, stream, cnt, ptrtmp, bsum, N);
    hipLaunchKernelGGL(k_scan_bsums, dim3(1), dim3(512), 0, stream, bsum, nb);
    hipLaunchKernelGGL(k_scan_finalize, dim3((N + 256) / 256), dim3(256), 0, stream,
                       ptrtmp, bsum, ptr, cursor, N, Et);

    const int nchunks = (Et + CHUNK - 1) / CHUNK;
    hipLaunchKernelGGL(k_scatter_r, dim3(nchunks * NR), dim3(256), 0, stream,
                       ei, E, Et, rngSize, cursor, srcs);

    hipLaunchKernelGGL(k_node1, dim3((N * NH + 255) / 256), dim3(256), 0, stream,
                       x, W1, as1, ad1, h1, a_s1, a_d1, N);

    hipLaunchKernelGGL(k_gat1, dim3((N + 3) / 4), dim3(256), 0, stream,
                       ptr, srcs, a_s1, a_d1, h1, b1, W2, as2, ad2, h2, a_s2, a_d2, N);

    hipLaunchKernelGGL(k_gat2, dim3((N * 16 + 255) / 256), dim3(256), 0, stream,
                       ptr, srcs, a_s2, a_d2, h2, b2, out, N);
}